// Round 4
// baseline (802.238 us; speedup 1.0000x reference)
//
#include <hip/hip_runtime.h>
#include <hip/hip_bf16.h>

// Problem constants (reference: BS=32, N=512)
#define BSZ 32
#define NN  512
#define G   8          // output rows (i,j1) per block in the fused kernel

// ============================================================================
// INSTRUMENTATION ROUND: REP=3 repeats the (idempotent) node+edge work inside
// one dispatch so it exceeds the ~283 µs harness re-poison fills and surfaces
// in the rocprof top-5 WITH counters (4 prior rounds: our kernels never
// appeared, so FETCH/WRITE/VALUBusy/Occupancy were never observed).
// absmax stays 0: every rep writes identical values. The asm memory barrier
// between reps prevents cross-rep store merging / load CSE.
// Single-pass time = (dur_R4 - dur_R3) / (REP-1).
// ============================================================================
#define REP 3

// Output flat offsets (elements, f32), in reference return order:
//  X_cat [32,512,32]       = 524288
//  C_cat [32,512,6]        =  98304
//  E1    [32,512,512,5]    = 41943040
//  E2    [32,512,512,5]    = 41943040
//  BD1   [32,512,512,3]    = 25165824
static const long O_XC = 0;
static const long O_CC = 524288L;
static const long O_E1 = 622592L;
static const long O_E2 = 42565632L;
static const long O_BD = 84508672L;

typedef float f32x4 __attribute__((ext_vector_type(4)));

// ---------------------------------------------------------------------------
// Kernel A: per-sample alignment map (unchanged — trivial cost).
// ---------------------------------------------------------------------------
__global__ __launch_bounds__(NN) void align_kernel(
    const int* __restrict__ amn, const int* __restrict__ ma,
    int* __restrict__ p2m)
{
    const int i = blockIdx.x;
    const int t = threadIdx.x;          // 0..511

    __shared__ int red[NN];
    __shared__ int table[NN + 1];

    const int a = ma[i * NN + t];
    red[t] = a;
    __syncthreads();
    for (int s = NN / 2; s > 0; s >>= 1) {
        if (t < s) red[t] = max(red[t], red[t + s]);
        __syncthreads();
    }
    const int prod_assign = red[0];

    table[t] = -1;
    if (t == 0) table[NN] = -1;
    __syncthreads();

    const int m = amn[i * NN + t];
    if (a == prod_assign && m > 0 && m <= NN) table[m] = t;
    __syncthreads();

    int p = -1;
    if (a < prod_assign && m > 0 && m <= NN) p = table[m];
    p2m[i * NN + t] = p;
}

// ---------------------------------------------------------------------------
// Fused kernel: identical work structure to round 3, wrapped in REP loop.
// ---------------------------------------------------------------------------
__global__ __launch_bounds__(256) void fused_kernel(
    const float* __restrict__ X,
    const float* __restrict__ E,
    const float* __restrict__ AC,
    const float* __restrict__ BD,
    const int* __restrict__ p2m,
    float* __restrict__ out)
{
    const int blk = blockIdx.x;         // 0..2047
    const int i   = blk >> 6;           // 64 blocks per sample
    const int j0  = (blk & 63) * G;     // first of G rows
    const int t   = threadIdx.x;

    __shared__ int sp[NN];
    sp[t]       = p2m[i * NN + t];
    sp[t + 256] = p2m[i * NN + t + 256];
    __syncthreads();

#pragma unroll 1
    for (int rep = 0; rep < REP; ++rep) {

    // ---- node features for rows j0..j0+G-1 ----
    if (t < G * 8) {                    // X_cat: G rows x 8 float4
        const int r = t >> 3, q = t & 7;
        const int j1 = j0 + r;
        const size_t idx = (size_t)i * NN + j1;
        const int p = sp[j1];
        float4 v = make_float4(0.f, 0.f, 0.f, 0.f);
        if (q < 4) {
            v = ((const float4*)(X + idx * 16))[q];
        } else if (p >= 0) {
            v = ((const float4*)(X + ((size_t)i * NN + p) * 16))[q - 4];
        }
        ((float4*)(out + O_XC + idx * 32))[q] = v;
    } else if (t < G * 8 + G * 2) {     // C_cat: G rows x 2 halves of 3 floats
        const int u = t - G * 8;
        const int r = u >> 1, h = u & 1;
        const int j1 = j0 + r;
        const size_t idx = (size_t)i * NN + j1;
        const int p = sp[j1];
        float* dst = out + O_CC + idx * 6 + h * 3;
        if (h == 0) {
            const float* src = AC + idx * 3;
#pragma unroll
            for (int c = 0; c < 3; ++c) dst[c] = src[c];
        } else if (p >= 0) {
            const float* src = AC + ((size_t)i * NN + p) * 3;
#pragma unroll
            for (int c = 0; c < 3; ++c) dst[c] = src[c];
        } else {
#pragma unroll
            for (int c = 0; c < 3; ++c) dst[c] = 0.0f;
        }
    }

    // ---- edge features: G rows, no barriers inside the loop ----
    for (int r = 0; r < G; ++r) {
        const int j1 = j0 + r;
        const size_t b = (size_t)i * NN + j1;
        const int p1 = sp[j1];          // block-uniform

        f32x4* oE1 = (f32x4*)(out + O_E1 + b * (NN * 5));
        f32x4* oE2 = (f32x4*)(out + O_E2 + b * (NN * 5));
        f32x4* oBD = (f32x4*)(out + O_BD + b * (NN * 3));

        if (p1 < 0) {
            // unmapped row: E1 = 0, E2 = onehot0, BD = 0 — pure fill
            const f32x4 z = {0.f, 0.f, 0.f, 0.f};
#pragma unroll
            for (int u = 0; u < 3; ++u) {
                const int f = t + u * 256;
                if (u < 2 || t < 128) {
                    f32x4 v2;
#pragma unroll
                    for (int k = 0; k < 4; ++k) {
                        const int g  = 4 * f + k;
                        const int j2 = g / 5;
                        const int c  = g - j2 * 5;
                        v2[k] = (c == 0) ? 1.0f : 0.0f;
                    }
                    oE1[f] = z;
                    oE2[f] = v2;
                }
            }
#pragma unroll
            for (int u = 0; u < 2; ++u) {
                const int f = t + u * 256;
                if (u < 1 || t < 128) oBD[f] = z;
            }
            continue;
        }

        const float* __restrict__ Erow = E  + ((size_t)i * NN + p1) * (NN * 5);
        const float* __restrict__ Brow = BD + ((size_t)i * NN + p1) * (NN * 3);

        // E1 + E2 (640 f32x4 each)
#pragma unroll
        for (int u = 0; u < 3; ++u) {
            const int f = t + u * 256;
            if (u < 2 || t < 128) {
                f32x4 v1, v2;
#pragma unroll
                for (int k = 0; k < 4; ++k) {
                    const int g   = 4 * f + k;
                    const int j2  = g / 5;          // magic-mul
                    const int c   = g - j2 * 5;
                    const int p2  = sp[j2];
                    const int p2c = p2 < 0 ? 0 : p2;
                    const float e = Erow[p2c * 5 + c];
                    const bool pair = (p2 >= 0);
                    v1[k] = pair ? e : 0.0f;
                    v2[k] = pair ? 0.0f : (c == 0 ? 1.0f : 0.0f);
                }
                oE1[f] = v1;
                oE2[f] = v2;
            }
        }

        // BD1 (384 f32x4)
#pragma unroll
        for (int u = 0; u < 2; ++u) {
            const int f = t + u * 256;
            if (u < 1 || t < 128) {
                f32x4 v;
#pragma unroll
                for (int k = 0; k < 4; ++k) {
                    const int g   = 4 * f + k;
                    const int j2  = g / 3;
                    const int c   = g - j2 * 3;
                    const int p2  = sp[j2];
                    const int p2c = p2 < 0 ? 0 : p2;
                    const float x = Brow[p2c * 3 + c];
                    v[k] = (p2 >= 0) ? x : 0.0f;
                }
                oBD[f] = v;
            }
        }
    }

    // Prevent cross-rep store merging / load CSE: compiler must assume memory
    // changed, so every rep re-executes all loads and stores.
    asm volatile("" ::: "memory");

    }  // rep
}

extern "C" void kernel_launch(void* const* d_in, const int* in_sizes, int n_in,
                              void* d_out, int out_size, void* d_ws, size_t ws_size,
                              hipStream_t stream) {
    const float* X  = (const float*)d_in[0];
    const float* E  = (const float*)d_in[1];
    const float* AC = (const float*)d_in[2];
    const float* BD = (const float*)d_in[3];
    const int* amn = (const int*)d_in[4];
    const int* ma  = (const int*)d_in[5];
    float* out = (float*)d_out;

    int* p2m = (int*)d_ws;   // 32*512 ints = 64 KB

    align_kernel<<<BSZ, NN, 0, stream>>>(amn, ma, p2m);
    fused_kernel<<<(BSZ * NN) / G, 256, 0, stream>>>(X, E, AC, BD, p2m, out);
}

// Round 5
// 593.554 us; speedup vs baseline: 1.3516x; 1.3516x over previous
//
#include <hip/hip_runtime.h>
#include <hip/hip_bf16.h>

// Problem constants (reference: BS=32, N=512)
#define BSZ 32
#define NN  512
#define G   8          // output rows (i,j1) per block in the fused kernel

// Output flat offsets (elements, f32), in reference return order:
//  X_cat [32,512,32]       = 524288
//  C_cat [32,512,6]        =  98304
//  E1    [32,512,512,5]    = 41943040
//  E2    [32,512,512,5]    = 41943040
//  BD1   [32,512,512,3]    = 25165824
static const long O_XC = 0;
static const long O_CC = 524288L;
static const long O_E1 = 622592L;
static const long O_E2 = 42565632L;
static const long O_BD = 84508672L;

typedef float f32x4 __attribute__((ext_vector_type(4)));

// ---------------------------------------------------------------------------
// Kernel A: per-sample alignment map (unchanged — trivial cost).
// p2m[i*N+j] = product position aligned to reactant j, or -1 if unmapped.
// ---------------------------------------------------------------------------
__global__ __launch_bounds__(NN) void align_kernel(
    const int* __restrict__ amn, const int* __restrict__ ma,
    int* __restrict__ p2m)
{
    const int i = blockIdx.x;
    const int t = threadIdx.x;          // 0..511

    __shared__ int red[NN];
    __shared__ int table[NN + 1];

    const int a = ma[i * NN + t];
    red[t] = a;
    __syncthreads();
    for (int s = NN / 2; s > 0; s >>= 1) {
        if (t < s) red[t] = max(red[t], red[t + s]);
        __syncthreads();
    }
    const int prod_assign = red[0];

    table[t] = -1;
    if (t == 0) table[NN] = -1;
    __syncthreads();

    const int m = amn[i * NN + t];
    if (a == prod_assign && m > 0 && m <= NN) table[m] = t;
    __syncthreads();

    int p = -1;
    if (a < prod_assign && m > 0 && m <= NN) p = table[m];
    p2m[i * NN + t] = p;
}

// ---------------------------------------------------------------------------
// Fused kernel (round 5): REP instrumentation removed; row assignment now
// INTERLEAVED for load balance.
//
// Round-4 counters (REP=3 dispatch): single pass ~118 µs @ 4.24 TB/s,
// WRITE=3x438 MB (no amplification), FETCH=196 MB (no over-fetch), VALUBusy
// 8.6%, bank conflicts negligible -> memory-bound but 28 µs off the ~90 µs
// roofline. Diagnosis: G=8 CONSECUTIVE rows/block meant half the blocks
// (rows 0..255, gather+read) did ~1.6x the traffic of the fill-only half
// (rows 256..511), and grid = exactly one residency wave (2048 blocks =
// 8/CU) -> no rebalancing; tail at ~half throughput.
// Fix: block blk owns rows (blk&63) + 64*r, r=0..7 -> exactly 4 mapped +
// 4 unmapped rows per block, uniform work, tail-free.
// ---------------------------------------------------------------------------
__global__ __launch_bounds__(256) void fused_kernel(
    const float* __restrict__ X,
    const float* __restrict__ E,
    const float* __restrict__ AC,
    const float* __restrict__ BD,
    const int* __restrict__ p2m,
    float* __restrict__ out)
{
    const int blk = blockIdx.x;         // 0..2047
    const int i   = blk >> 6;           // 64 blocks per sample
    const int jb  = blk & 63;           // base row; block owns jb + 64*r
    const int t   = threadIdx.x;

    __shared__ int sp[NN];
    sp[t]       = p2m[i * NN + t];
    sp[t + 256] = p2m[i * NN + t + 256];
    __syncthreads();

    // ---- node features for the block's 8 rows ----
    if (t < G * 8) {                    // X_cat: 8 rows x 8 float4
        const int r = t >> 3, q = t & 7;
        const int j1 = jb + (r << 6);
        const size_t idx = (size_t)i * NN + j1;
        const int p = sp[j1];
        float4 v = make_float4(0.f, 0.f, 0.f, 0.f);
        if (q < 4) {
            v = ((const float4*)(X + idx * 16))[q];
        } else if (p >= 0) {
            v = ((const float4*)(X + ((size_t)i * NN + p) * 16))[q - 4];
        }
        ((float4*)(out + O_XC + idx * 32))[q] = v;
    } else if (t < G * 8 + G * 2) {     // C_cat: 8 rows x 2 halves of 3 floats
        const int u = t - G * 8;
        const int r = u >> 1, h = u & 1;
        const int j1 = jb + (r << 6);
        const size_t idx = (size_t)i * NN + j1;
        const int p = sp[j1];
        float* dst = out + O_CC + idx * 6 + h * 3;
        if (h == 0) {
            const float* src = AC + idx * 3;
#pragma unroll
            for (int c = 0; c < 3; ++c) dst[c] = src[c];
        } else if (p >= 0) {
            const float* src = AC + ((size_t)i * NN + p) * 3;
#pragma unroll
            for (int c = 0; c < 3; ++c) dst[c] = src[c];
        } else {
#pragma unroll
            for (int c = 0; c < 3; ++c) dst[c] = 0.0f;
        }
    }

    // ---- edge features: 8 interleaved rows, no barriers inside the loop ----
    for (int r = 0; r < G; ++r) {
        const int j1 = jb + (r << 6);
        const size_t b = (size_t)i * NN + j1;
        const int p1 = sp[j1];          // block-uniform

        f32x4* oE1 = (f32x4*)(out + O_E1 + b * (NN * 5));
        f32x4* oE2 = (f32x4*)(out + O_E2 + b * (NN * 5));
        f32x4* oBD = (f32x4*)(out + O_BD + b * (NN * 3));

        if (p1 < 0) {
            // unmapped row: E1 = 0, E2 = onehot0, BD = 0 — pure fill
            const f32x4 z = {0.f, 0.f, 0.f, 0.f};
#pragma unroll
            for (int u = 0; u < 3; ++u) {
                const int f = t + u * 256;
                if (u < 2 || t < 128) {
                    f32x4 v2;
#pragma unroll
                    for (int k = 0; k < 4; ++k) {
                        const int g  = 4 * f + k;
                        const int j2 = g / 5;
                        const int c  = g - j2 * 5;
                        v2[k] = (c == 0) ? 1.0f : 0.0f;
                    }
                    oE1[f] = z;
                    oE2[f] = v2;
                }
            }
#pragma unroll
            for (int u = 0; u < 2; ++u) {
                const int f = t + u * 256;
                if (u < 1 || t < 128) oBD[f] = z;
            }
            continue;
        }

        const float* __restrict__ Erow = E  + ((size_t)i * NN + p1) * (NN * 5);
        const float* __restrict__ Brow = BD + ((size_t)i * NN + p1) * (NN * 3);

        // E1 + E2 (640 f32x4 each)
#pragma unroll
        for (int u = 0; u < 3; ++u) {
            const int f = t + u * 256;
            if (u < 2 || t < 128) {
                f32x4 v1, v2;
#pragma unroll
                for (int k = 0; k < 4; ++k) {
                    const int g   = 4 * f + k;
                    const int j2  = g / 5;          // magic-mul
                    const int c   = g - j2 * 5;
                    const int p2  = sp[j2];
                    const int p2c = p2 < 0 ? 0 : p2;
                    const float e = Erow[p2c * 5 + c];
                    const bool pair = (p2 >= 0);
                    v1[k] = pair ? e : 0.0f;
                    v2[k] = pair ? 0.0f : (c == 0 ? 1.0f : 0.0f);
                }
                oE1[f] = v1;
                oE2[f] = v2;
            }
        }

        // BD1 (384 f32x4)
#pragma unroll
        for (int u = 0; u < 2; ++u) {
            const int f = t + u * 256;
            if (u < 1 || t < 128) {
                f32x4 v;
#pragma unroll
                for (int k = 0; k < 4; ++k) {
                    const int g   = 4 * f + k;
                    const int j2  = g / 3;
                    const int c   = g - j2 * 3;
                    const int p2  = sp[j2];
                    const int p2c = p2 < 0 ? 0 : p2;
                    const float x = Brow[p2c * 3 + c];
                    v[k] = (p2 >= 0) ? x : 0.0f;
                }
                oBD[f] = v;
            }
        }
    }
}

extern "C" void kernel_launch(void* const* d_in, const int* in_sizes, int n_in,
                              void* d_out, int out_size, void* d_ws, size_t ws_size,
                              hipStream_t stream) {
    const float* X  = (const float*)d_in[0];
    const float* E  = (const float*)d_in[1];
    const float* AC = (const float*)d_in[2];
    const float* BD = (const float*)d_in[3];
    const int* amn = (const int*)d_in[4];
    const int* ma  = (const int*)d_in[5];
    float* out = (float*)d_out;

    int* p2m = (int*)d_ws;   // 32*512 ints = 64 KB

    align_kernel<<<BSZ, NN, 0, stream>>>(amn, ma, p2m);
    fused_kernel<<<(BSZ * NN) / G, 256, 0, stream>>>(X, E, AC, BD, p2m, out);
}